// Round 3
// baseline (145.498 us; speedup 1.0000x reference)
//
#include <hip/hip_runtime.h>
#include <math.h>

typedef __bf16 bf16x8 __attribute__((ext_vector_type(8)));
typedef float f32x4 __attribute__((ext_vector_type(4)));
typedef unsigned short u16;
typedef unsigned int u32;

constexpr int BATCH = 2048;
constexpr int ROWS  = 4096;   // 2 steps x 2048
constexpr int HID   = 512;
constexpr int NACT  = 8;

__device__ __forceinline__ float gelu_f(float x) {
    return 0.5f * x * (1.0f + erff(x * 0.70710678118654752f));
}
__device__ __forceinline__ u16 f2bf(float f) {
    u32 u = __float_as_uint(f);
    return (u16)((u + 0x7FFFu + ((u >> 16) & 1u)) >> 16);
}
__device__ __forceinline__ float bf2f(u16 h) {
    return __uint_as_float(((u32)h) << 16);
}

// ---------------------------------------------------------------------------
// K_prep: z<4 -> transpose + hi/lo-split weight layer z into wt
//         z==4 -> temb @ W_in[14:526] split-K partials (16 blocks used)
// wt layout per layer l: hi plane [n][k] at l*524288 (u16), lo at +262144
// ---------------------------------------------------------------------------
__global__ __launch_bounds__(256) void k_prep(
        const float* __restrict__ W1, const float* __restrict__ W2,
        const float* __restrict__ W3, const float* __restrict__ W4,
        const float* __restrict__ W_in,
        u16* __restrict__ wt, float* __restrict__ partials) {
    int z = blockIdx.z;
    if (z == 4) {
        if (blockIdx.x >= 16 || blockIdx.y != 0) return;
        __shared__ float temb[32];
        int bz = blockIdx.x, t = threadIdx.x;
        if (t < 32) {
            int k = bz * 32 + t;
            int p = k >> 1;
            float div = expf((float)(2 * p) * (-9.210340371976184f / 512.0f));
            temb[t] = (k & 1) ? cosf(49.0f * div) : sinf(49.0f * div);
        }
        __syncthreads();
#pragma unroll
        for (int half = 0; half < 2; ++half) {
            int col = half * 256 + t;
            float acc = 0.f;
            for (int kk = 0; kk < 32; ++kk)
                acc += temb[kk] * W_in[(size_t)(14 + bz * 32 + kk) * HID + col];
            partials[bz * HID + col] = acc;
        }
        return;
    }
    __shared__ float tile[32][33];
    const float* Ws[4] = {W1, W2, W3, W4};
    const float* W = Ws[z];
    u16* wh = wt + (size_t)z * 524288;
    u16* wl = wh + 262144;
    int kt = blockIdx.x * 32, nt = blockIdx.y * 32, t = threadIdx.x;
    int c = t & 31, r = t >> 5;
#pragma unroll
    for (int p = 0; p < 4; ++p)
        tile[r + p * 8][c] = W[(size_t)(kt + r + p * 8) * HID + nt + c];
    __syncthreads();
#pragma unroll
    for (int p = 0; p < 4; ++p) {
        int nl = r + p * 8, kl = c;
        float v = tile[kl][nl];
        u16 h = f2bf(v);
        u16 l2 = f2bf(v - bf2f(h));
        size_t o = (size_t)(nt + nl) * HID + kt + kl;
        wh[o] = h;
        wl[o] = l2;
    }
}

// K_setup2: reduce partials + b_in -> bias_comb
__global__ void k_setup2(const float* __restrict__ b_in, const float* __restrict__ partials,
                         float* __restrict__ bias_comb) {
    int t = threadIdx.x;
    float a = b_in[t];
    for (int b = 0; b < 16; ++b) a += partials[b * HID + t];
    bias_comb[t] = a;
}

// ---------------------------------------------------------------------------
// K1: input layer -> bf16 hi/lo planes
// ---------------------------------------------------------------------------
__global__ __launch_bounds__(256) void k_layer_in2(
        const float* __restrict__ x_pre, const float* __restrict__ noise,
        const float* __restrict__ W_in, const float* __restrict__ bias_comb,
        u16* __restrict__ Yh, u16* __restrict__ Yl) {
    int idx = blockIdx.x * 256 + threadIdx.x;
    int r = idx >> 9, n = idx & 511, s = r >> 11, b = r & 2047;
    float acc = bias_comb[n];
    const float* xp = &x_pre[b * 6];
#pragma unroll
    for (int j = 0; j < 6; ++j) acc += xp[j] * W_in[j * HID + n];
    const float* nz = &noise[(s * BATCH + b) * NACT];
#pragma unroll
    for (int j = 0; j < 8; ++j) acc += nz[j] * W_in[(6 + j) * HID + n];
    float g = gelu_f(acc);
    u16 h = f2bf(g);
    Yh[idx] = h;
    Yl[idx] = f2bf(g - bf2f(h));
}

// ---------------------------------------------------------------------------
// GEMM: Y = gelu(A @ W + b) via split-bf16 3-pass MFMA.
// BM=128, BN=64, 4 waves, wave tile 64x32 (4x2 fragments of 16x16x32), BK=32.
// LDS fragments stored in lane-linear order (conflict-free b128 reads).
// ---------------------------------------------------------------------------
__global__ __launch_bounds__(256) void k_gemm_mfma2(
        const u16* __restrict__ Ah, const u16* __restrict__ Al,
        const u16* __restrict__ Wh, const u16* __restrict__ Wl,
        const float* __restrict__ bias,
        u16* __restrict__ Yh, u16* __restrict__ Yl) {
    __shared__ __align__(16) u16 ldsA[2][2][8][512]; // [buf][plane][grp16rows][16x32]
    __shared__ __align__(16) u16 ldsB[2][2][4][512];
    int tid = threadIdx.x, lane = tid & 63, w = tid >> 6;
    int wm = w >> 1, wn = w & 1;
    int m0 = blockIdx.x * 128, n0 = blockIdx.y * 64;
    int l15 = lane & 15, k8 = (lane >> 4) * 8;

    // staging source pointers: lane covers (row = l&15 of group, kchunk = (l>>4)*8)
    const u16* pah0 = Ah + (size_t)(m0 + w * 16 + l15) * HID + k8;
    const u16* pah1 = pah0 + 64 * HID;
    const u16* pal0 = Al + (size_t)(m0 + w * 16 + l15) * HID + k8;
    const u16* pal1 = pal0 + 64 * HID;
    const u16* pbh  = Wh + (size_t)(n0 + w * 16 + l15) * HID + k8;
    const u16* pbl  = Wl + (size_t)(n0 + w * 16 + l15) * HID + k8;

    auto stage = [&](int c, int bb) {
        int off = c * 32;
        __builtin_amdgcn_global_load_lds((const __attribute__((address_space(1))) void*)(pah0 + off),
            (__attribute__((address_space(3))) void*)&ldsA[bb][0][w][0], 16, 0, 0);
        __builtin_amdgcn_global_load_lds((const __attribute__((address_space(1))) void*)(pah1 + off),
            (__attribute__((address_space(3))) void*)&ldsA[bb][0][w + 4][0], 16, 0, 0);
        __builtin_amdgcn_global_load_lds((const __attribute__((address_space(1))) void*)(pal0 + off),
            (__attribute__((address_space(3))) void*)&ldsA[bb][1][w][0], 16, 0, 0);
        __builtin_amdgcn_global_load_lds((const __attribute__((address_space(1))) void*)(pal1 + off),
            (__attribute__((address_space(3))) void*)&ldsA[bb][1][w + 4][0], 16, 0, 0);
        __builtin_amdgcn_global_load_lds((const __attribute__((address_space(1))) void*)(pbh + off),
            (__attribute__((address_space(3))) void*)&ldsB[bb][0][w][0], 16, 0, 0);
        __builtin_amdgcn_global_load_lds((const __attribute__((address_space(1))) void*)(pbl + off),
            (__attribute__((address_space(3))) void*)&ldsB[bb][1][w][0], 16, 0, 0);
    };

    f32x4 zero = {0.f, 0.f, 0.f, 0.f};
    f32x4 acc[4][2];
#pragma unroll
    for (int i = 0; i < 4; ++i)
#pragma unroll
        for (int j = 0; j < 2; ++j) acc[i][j] = zero;

    stage(0, 0);
    for (int c = 0; c < 16; ++c) {
        int bb = c & 1;
        __syncthreads();
        if (c < 15) stage(c + 1, bb ^ 1);
        bf16x8 ah[4], al[4], bh[2], bl[2];
#pragma unroll
        for (int i = 0; i < 4; ++i) {
            ah[i] = *(const bf16x8*)&ldsA[bb][0][wm * 4 + i][lane * 8];
            al[i] = *(const bf16x8*)&ldsA[bb][1][wm * 4 + i][lane * 8];
        }
#pragma unroll
        for (int j = 0; j < 2; ++j) {
            bh[j] = *(const bf16x8*)&ldsB[bb][0][wn * 2 + j][lane * 8];
            bl[j] = *(const bf16x8*)&ldsB[bb][1][wn * 2 + j][lane * 8];
        }
#pragma unroll
        for (int i = 0; i < 4; ++i)
#pragma unroll
            for (int j = 0; j < 2; ++j) {
                acc[i][j] = __builtin_amdgcn_mfma_f32_16x16x32_bf16(ah[i], bh[j], acc[i][j], 0, 0, 0);
                acc[i][j] = __builtin_amdgcn_mfma_f32_16x16x32_bf16(ah[i], bl[j], acc[i][j], 0, 0, 0);
                acc[i][j] = __builtin_amdgcn_mfma_f32_16x16x32_bf16(al[i], bh[j], acc[i][j], 0, 0, 0);
            }
    }

#pragma unroll
    for (int i = 0; i < 4; ++i) {
        int row0 = m0 + wm * 64 + i * 16 + (lane >> 4) * 4;
#pragma unroll
        for (int j = 0; j < 2; ++j) {
            int col = n0 + wn * 32 + j * 16 + l15;
            float bia = bias[col];
#pragma unroll
            for (int r2 = 0; r2 < 4; ++r2) {
                float g = gelu_f(acc[i][j][r2] + bia);
                u16 h = f2bf(g);
                size_t o = (size_t)(row0 + r2) * HID + col;
                Yh[o] = h;
                Yl[o] = f2bf(g - bf2f(h));
            }
        }
    }
}

// ---------------------------------------------------------------------------
// K6: output layer for BOTH steps + DDIM + tanh + FK + select + write d_out.
// One wave per batch element; lanes 0 and 1 run FK for step 0/1 in parallel.
// ---------------------------------------------------------------------------
__device__ void mat4mul(float C[4][4], const float A[4][4], const float Bm[4][4]) {
#pragma unroll
    for (int i = 0; i < 4; ++i)
#pragma unroll
        for (int j = 0; j < 4; ++j) {
            float s = A[i][0] * Bm[0][j];
            s += A[i][1] * Bm[1][j];
            s += A[i][2] * Bm[2][j];
            s += A[i][3] * Bm[3][j];
            C[i][j] = s;
        }
}

__global__ __launch_bounds__(256) void k_out_fk3(
        const u16* __restrict__ Yh, const u16* __restrict__ Yl,
        const float* __restrict__ W_out, const float* __restrict__ b_out,
        const float* __restrict__ noise, const float* __restrict__ x_pre,
        float* __restrict__ out, float c1, float c2, float c3) {
    int b = blockIdx.x * 4 + (threadIdx.x >> 6);
    int lane = threadIdx.x & 63;

    float acc0[8] = {0, 0, 0, 0, 0, 0, 0, 0};
    float acc1[8] = {0, 0, 0, 0, 0, 0, 0, 0};
    const u16* yh0 = &Yh[(size_t)b * HID];
    const u16* yl0 = &Yl[(size_t)b * HID];
    const u16* yh1 = &Yh[(size_t)(BATCH + b) * HID];
    const u16* yl1 = &Yl[(size_t)(BATCH + b) * HID];
#pragma unroll
    for (int it = 0; it < 8; ++it) {
        int k = lane + it * 64;
        float4 w0 = ((const float4*)&W_out[k * NACT])[0];
        float4 w1 = ((const float4*)&W_out[k * NACT])[1];
        float ya = bf2f(yh0[k]) + bf2f(yl0[k]);
        float yb = bf2f(yh1[k]) + bf2f(yl1[k]);
        acc0[0] += ya * w0.x; acc0[1] += ya * w0.y; acc0[2] += ya * w0.z; acc0[3] += ya * w0.w;
        acc0[4] += ya * w1.x; acc0[5] += ya * w1.y; acc0[6] += ya * w1.z; acc0[7] += ya * w1.w;
        acc1[0] += yb * w0.x; acc1[1] += yb * w0.y; acc1[2] += yb * w0.z; acc1[3] += yb * w0.w;
        acc1[4] += yb * w1.x; acc1[5] += yb * w1.y; acc1[6] += yb * w1.z; acc1[7] += yb * w1.w;
    }
    // butterfly reduce: all lanes end with full sums
#pragma unroll
    for (int n = 0; n < 8; ++n) {
#pragma unroll
        for (int off = 32; off > 0; off >>= 1) {
            acc0[n] += __shfl_xor(acc0[n], off, 64);
            acc1[n] += __shfl_xor(acc1[n], off, 64);
        }
    }

    float jq[8] = {0, 0, 0, 0, 0, 0, 0, 0};
    float err = 0.f;
    if (lane < 2) {
        int s = lane;
        const float* accp = (s == 0) ? acc0 : acc1;
        const float HIf[8] = {
            (float)(35.0 * M_PI / 180.0), (float)(-60.0 * M_PI / 180.0), 3.94f,
            (float)(155.0 * M_PI / 180.0), (float)(-55.0 * M_PI / 180.0),
            (float)M_PI, (float)(5.0 * M_PI / 180.0), 3.71f};
        const float LOf[8] = {
            (float)(-35.0 * M_PI / 180.0), (float)(-155.0 * M_PI / 180.0), 2.59f,
            (float)(60.0 * M_PI / 180.0), (float)(-125.0 * M_PI / 180.0),
            (float)(-M_PI), (float)(-90.0 * M_PI / 180.0), 2.5f};
        const float* nzp = &noise[(s * BATCH + b) * NACT];
#pragma unroll
        for (int n = 0; n < 8; ++n) {
            float o = accp[n] + b_out[n];
            float z = c1 * nzp[n] + c2 * o + c3 * nzp[n];
            float jn = (tanhf(z * 0.1f) + 1.0f) * 0.5f;
            jq[n] = jn * (HIf[n] - LOf[n]) + LOf[n];
        }
        const float a_[8]  = {0.0f, 0.16f, 0.07f, 0.0f, 0.1334f, 0.0f, 0.15f, 0.3625f};
        const float ca_[8] = {1.f, 0.f, 0.f, 0.f, 0.f, 0.f, 0.f, 0.f};
        const float sa_[8] = {0.f, -1.f, -1.f, 1.f, -1.f, -1.f, 1.f, -1.f};
        float d_[8] = {0.0f, 0.0f, jq[2], 0.0f, -0.1316f, 1.0105f, 0.52f, jq[7]};
        float th[8] = {jq[0], jq[1], 0.0f, jq[3], jq[4], jq[5], jq[6], 0.0f};
        float T[4][4], M[4][4], Tn[4][4];
#pragma unroll
        for (int j = 0; j < 8; ++j) {
            float ct = cosf(th[j]);
            float st = sinf(th[j]);
            M[0][0] = ct;          M[0][1] = -st;         M[0][2] = 0.0f;    M[0][3] = a_[j];
            M[1][0] = st * ca_[j]; M[1][1] = ct * ca_[j]; M[1][2] = -sa_[j]; M[1][3] = -sa_[j] * d_[j];
            M[2][0] = st * sa_[j]; M[2][1] = ct * sa_[j]; M[2][2] = ca_[j];  M[2][3] = ca_[j] * d_[j];
            M[3][0] = 0.0f;        M[3][1] = 0.0f;        M[3][2] = 0.0f;    M[3][3] = 1.0f;
            if (j == 0) {
#pragma unroll
                for (int i = 0; i < 4; ++i)
#pragma unroll
                    for (int cc = 0; cc < 4; ++cc) T[i][cc] = M[i][cc];
            } else {
                mat4mul(Tn, T, M);
#pragma unroll
                for (int i = 0; i < 4; ++i)
#pragma unroll
                    for (int cc = 0; cc < 4; ++cc) T[i][cc] = Tn[i][cc];
            }
        }
        float e1x = T[0][2] * 3.75f;
        float e1y = T[1][2] * 3.75f;
        float e1z = T[2][2] * 3.75f;
        float p0 = T[0][3];
        float p1 = T[1][3];
        float p2 = T[2][3] + 1.702f;
        float p3 = e1x + T[0][3];
        float p4 = e1y + T[1][3];
        float p5 = e1z + T[2][3] + 1.702f;
        const float* xp = &x_pre[b * 6];
        float dx0 = 100.0f * p0 - xp[0];
        float dx1 = 100.0f * p1 - xp[1];
        float dx2 = 100.0f * p2 - xp[2];
        float dx3 = 100.0f * p3 - xp[3];
        float dx4 = 100.0f * p4 - xp[4];
        float dx5 = 100.0f * p5 - xp[5];
        err = sqrtf(dx0 * dx0 + dx1 * dx1 + dx2 * dx2) +
              sqrtf(dx3 * dx3 + dx4 * dx4 + dx5 * dx5);
    }
    float e0 = __shfl(err, 0, 64);
    float e1 = __shfl(err, 1, 64);
    int sel = (e1 < e0) ? 1 : 0;   // first index wins ties
    float jsel[8];
#pragma unroll
    for (int n = 0; n < 8; ++n) jsel[n] = __shfl(jq[n], sel, 64);
    if (lane == 0) {
#pragma unroll
        for (int n = 0; n < 8; ++n) out[b * NACT + n] = jsel[n];
    }
}

// ===========================================================================
extern "C" void kernel_launch(void* const* d_in, const int* in_sizes, int n_in,
                              void* d_out, int out_size, void* d_ws, size_t ws_size,
                              hipStream_t stream) {
    const float* x_pre = (const float*)d_in[0];
    const float* noise = (const float*)d_in[1];
    const float* W_in  = (const float*)d_in[2];
    const float* b_in  = (const float*)d_in[3];
    const float* W1    = (const float*)d_in[4];
    const float* b1    = (const float*)d_in[5];
    const float* W2    = (const float*)d_in[6];
    const float* b2    = (const float*)d_in[7];
    const float* W3    = (const float*)d_in[8];
    const float* b3    = (const float*)d_in[9];
    const float* W4    = (const float*)d_in[10];
    const float* b4    = (const float*)d_in[11];
    const float* W_out = (const float*)d_in[12];
    const float* b_out = (const float*)d_in[13];

    // DDIM last-step coefficients (only the last loop iteration matters:
    // z is overwritten every iteration in the reference, nz never updated).
    double ab_c = exp(-0.1 * 50.0 / 1000.0 - 0.5 * (10.0 - 0.1) * 2500.0 / 1.0e6);
    float c1 = (float)sqrt(1.0 / ab_c);
    float c2 = (float)(-sqrt((1.0 - ab_c) / ab_c));
    float c3 = (float)sqrt(1.0 - ab_c);

    char* base = (char*)d_ws;
    u16* Ah = (u16*)base;                    // 4096x512 u16 = 4 MB
    u16* Al = Ah + 2097152;
    u16* Bh = Al + 2097152;
    u16* Bl = Bh + 2097152;
    u16* wt = (u16*)(base + 16777216);       // 4 layers x (hi,lo) [n][k] = 4 MB
    float* partials  = (float*)(base + 16777216 + 4194304); // 16x512
    float* bias_comb = partials + 16 * HID;

    k_prep<<<dim3(16, 16, 5), 256, 0, stream>>>(W1, W2, W3, W4, W_in, wt, partials);
    k_setup2<<<1, 512, 0, stream>>>(b_in, partials, bias_comb);
    k_layer_in2<<<ROWS * HID / 256, 256, 0, stream>>>(x_pre, noise, W_in, bias_comb, Ah, Al);
    dim3 g(ROWS / 128, HID / 64);
    k_gemm_mfma2<<<g, 256, 0, stream>>>(Ah, Al, wt + 0 * 524288, wt + 0 * 524288 + 262144, b1, Bh, Bl);
    k_gemm_mfma2<<<g, 256, 0, stream>>>(Bh, Bl, wt + 1 * 524288, wt + 1 * 524288 + 262144, b2, Ah, Al);
    k_gemm_mfma2<<<g, 256, 0, stream>>>(Ah, Al, wt + 2 * 524288, wt + 2 * 524288 + 262144, b3, Bh, Bl);
    k_gemm_mfma2<<<g, 256, 0, stream>>>(Bh, Bl, wt + 3 * 524288, wt + 3 * 524288 + 262144, b4, Ah, Al);
    k_out_fk3<<<BATCH / 4, 256, 0, stream>>>(Ah, Al, W_out, b_out, noise, x_pre,
                                             (float*)d_out, c1, c2, c3);
}

// Round 4
// 114.782 us; speedup vs baseline: 1.2676x; 1.2676x over previous
//
#include <hip/hip_runtime.h>
#include <math.h>

typedef __bf16 bf16x8 __attribute__((ext_vector_type(8)));
typedef float f32x4 __attribute__((ext_vector_type(4)));
typedef unsigned short u16;
typedef unsigned int u32;

constexpr int BATCH = 2048;
constexpr int ROWS  = 4096;   // 2 steps x 2048
constexpr int HID   = 512;
constexpr int NACT  = 8;

__device__ __forceinline__ float gelu_f(float x) {
    return 0.5f * x * (1.0f + erff(x * 0.70710678118654752f));
}
__device__ __forceinline__ u16 f2bf(float f) {
    u32 u = __float_as_uint(f);
    return (u16)((u + 0x7FFFu + ((u >> 16) & 1u)) >> 16);
}
__device__ __forceinline__ float bf2f(u16 h) {
    return __uint_as_float(((u32)h) << 16);
}

// ---------------------------------------------------------------------------
// K_prep: z<4 -> transpose + hi/lo-split weight layer z into wt
//         z==4 -> temb @ W_in[14:526] split-K partials (16 blocks used)
// wt layout per layer l: hi plane [n][k] at l*524288 (u16), lo at +262144
// ---------------------------------------------------------------------------
__global__ __launch_bounds__(256) void k_prep(
        const float* __restrict__ W1, const float* __restrict__ W2,
        const float* __restrict__ W3, const float* __restrict__ W4,
        const float* __restrict__ W_in,
        u16* __restrict__ wt, float* __restrict__ partials) {
    int z = blockIdx.z;
    if (z == 4) {
        if (blockIdx.x >= 16 || blockIdx.y != 0) return;
        __shared__ float temb[32];
        int bz = blockIdx.x, t = threadIdx.x;
        if (t < 32) {
            int k = bz * 32 + t;
            int p = k >> 1;
            float div = expf((float)(2 * p) * (-9.210340371976184f / 512.0f));
            temb[t] = (k & 1) ? cosf(49.0f * div) : sinf(49.0f * div);
        }
        __syncthreads();
#pragma unroll
        for (int half = 0; half < 2; ++half) {
            int col = half * 256 + t;
            float acc = 0.f;
            for (int kk = 0; kk < 32; ++kk)
                acc += temb[kk] * W_in[(size_t)(14 + bz * 32 + kk) * HID + col];
            partials[bz * HID + col] = acc;
        }
        return;
    }
    __shared__ float tile[32][33];
    const float* Ws[4] = {W1, W2, W3, W4};
    const float* W = Ws[z];
    u16* wh = wt + (size_t)z * 524288;
    u16* wl = wh + 262144;
    int kt = blockIdx.x * 32, nt = blockIdx.y * 32, t = threadIdx.x;
    int c = t & 31, r = t >> 5;
#pragma unroll
    for (int p = 0; p < 4; ++p)
        tile[r + p * 8][c] = W[(size_t)(kt + r + p * 8) * HID + nt + c];
    __syncthreads();
#pragma unroll
    for (int p = 0; p < 4; ++p) {
        int nl = r + p * 8, kl = c;
        float v = tile[kl][nl];
        u16 h = f2bf(v);
        u16 l2 = f2bf(v - bf2f(h));
        size_t o = (size_t)(nt + nl) * HID + kt + kl;
        wh[o] = h;
        wl[o] = l2;
    }
}

// K_setup2: reduce partials + b_in -> bias_comb
__global__ void k_setup2(const float* __restrict__ b_in, const float* __restrict__ partials,
                         float* __restrict__ bias_comb) {
    int t = threadIdx.x;
    float a = b_in[t];
    for (int b = 0; b < 16; ++b) a += partials[b * HID + t];
    bias_comb[t] = a;
}

// ---------------------------------------------------------------------------
// K1: input layer -> bf16 hi/lo planes
// ---------------------------------------------------------------------------
__global__ __launch_bounds__(256) void k_layer_in2(
        const float* __restrict__ x_pre, const float* __restrict__ noise,
        const float* __restrict__ W_in, const float* __restrict__ bias_comb,
        u16* __restrict__ Yh, u16* __restrict__ Yl) {
    int idx = blockIdx.x * 256 + threadIdx.x;
    int r = idx >> 9, n = idx & 511, s = r >> 11, b = r & 2047;
    float acc = bias_comb[n];
    const float* xp = &x_pre[b * 6];
#pragma unroll
    for (int j = 0; j < 6; ++j) acc += xp[j] * W_in[j * HID + n];
    const float* nz = &noise[(s * BATCH + b) * NACT];
#pragma unroll
    for (int j = 0; j < 8; ++j) acc += nz[j] * W_in[(6 + j) * HID + n];
    float g = gelu_f(acc);
    u16 h = f2bf(g);
    Yh[idx] = h;
    Yl[idx] = f2bf(g - bf2f(h));
}

// ---------------------------------------------------------------------------
// GEMM: Y = gelu(A @ W + b) via split-bf16 3-pass MFMA.
// BM=BN=64, 4 waves (wave tile 32x32), BK=32.
// T3/T4 pipeline: 3 LDS buffers, 2-deep prefetch, counted vmcnt (never 0
// in-loop), ONE raw s_barrier per K-step (no __syncthreads drain).
// Safety: stage(c+2) overwrites buf[(c-1)%3]; all its readers passed the
// top-of-c barrier with lgkmcnt satisfied before it is issued.
// ---------------------------------------------------------------------------
__global__ __launch_bounds__(256) void k_gemm_mfma3(
        const u16* __restrict__ Ah, const u16* __restrict__ Al,
        const u16* __restrict__ Wh, const u16* __restrict__ Wl,
        const float* __restrict__ bias,
        u16* __restrict__ Yh, u16* __restrict__ Yl) {
    __shared__ __align__(16) u16 lds[3][4][4][512]; // [buf][plane Ah,Al,Wh,Wl][grp16][16x32]
    int tid = threadIdx.x, lane = tid & 63, w = tid >> 6;
    int wm = w >> 1, wn = w & 1;
    int m0 = blockIdx.x * 64, n0 = blockIdx.y * 64;
    int l15 = lane & 15, k8 = (lane >> 4) * 8;

    const u16* gp0 = Ah + (size_t)(m0 + w * 16 + l15) * HID + k8;
    const u16* gp1 = Al + (size_t)(m0 + w * 16 + l15) * HID + k8;
    const u16* gp2 = Wh + (size_t)(n0 + w * 16 + l15) * HID + k8;
    const u16* gp3 = Wl + (size_t)(n0 + w * 16 + l15) * HID + k8;

    auto stage = [&](int c, int bb) {
        int off = c * 32;
        __builtin_amdgcn_global_load_lds((const __attribute__((address_space(1))) void*)(gp0 + off),
            (__attribute__((address_space(3))) void*)&lds[bb][0][w][0], 16, 0, 0);
        __builtin_amdgcn_global_load_lds((const __attribute__((address_space(1))) void*)(gp1 + off),
            (__attribute__((address_space(3))) void*)&lds[bb][1][w][0], 16, 0, 0);
        __builtin_amdgcn_global_load_lds((const __attribute__((address_space(1))) void*)(gp2 + off),
            (__attribute__((address_space(3))) void*)&lds[bb][2][w][0], 16, 0, 0);
        __builtin_amdgcn_global_load_lds((const __attribute__((address_space(1))) void*)(gp3 + off),
            (__attribute__((address_space(3))) void*)&lds[bb][3][w][0], 16, 0, 0);
    };

    f32x4 zero = {0.f, 0.f, 0.f, 0.f};
    f32x4 acc[2][2] = {{zero, zero}, {zero, zero}};

    stage(0, 0);
    stage(1, 1);
#pragma unroll
    for (int c = 0; c < 16; ++c) {
        int bb = c % 3;
        // wait for stage(c) only: leave stage(c+1)'s 4 loads in flight
        if (c < 15) {
            asm volatile("s_waitcnt vmcnt(4)" ::: "memory");
        } else {
            asm volatile("s_waitcnt vmcnt(0)" ::: "memory");
        }
        __builtin_amdgcn_s_barrier();
        __builtin_amdgcn_sched_barrier(0);

        bf16x8 ah[2], al[2], bh[2], bl[2];
#pragma unroll
        for (int i = 0; i < 2; ++i) {
            ah[i] = *(const bf16x8*)&lds[bb][0][wm * 2 + i][lane * 8];
            al[i] = *(const bf16x8*)&lds[bb][1][wm * 2 + i][lane * 8];
            bh[i] = *(const bf16x8*)&lds[bb][2][wn * 2 + i][lane * 8];
            bl[i] = *(const bf16x8*)&lds[bb][3][wn * 2 + i][lane * 8];
        }
        __builtin_amdgcn_s_setprio(1);
#pragma unroll
        for (int i = 0; i < 2; ++i)
#pragma unroll
            for (int j = 0; j < 2; ++j) {
                acc[i][j] = __builtin_amdgcn_mfma_f32_16x16x32_bf16(ah[i], bh[j], acc[i][j], 0, 0, 0);
                acc[i][j] = __builtin_amdgcn_mfma_f32_16x16x32_bf16(ah[i], bl[j], acc[i][j], 0, 0, 0);
                acc[i][j] = __builtin_amdgcn_mfma_f32_16x16x32_bf16(al[i], bh[j], acc[i][j], 0, 0, 0);
            }
        __builtin_amdgcn_s_setprio(0);
        if (c < 14) stage(c + 2, (c + 2) % 3);
    }

#pragma unroll
    for (int i = 0; i < 2; ++i) {
        int row0 = m0 + wm * 32 + i * 16 + (lane >> 4) * 4;
#pragma unroll
        for (int j = 0; j < 2; ++j) {
            int col = n0 + wn * 32 + j * 16 + l15;
            float bia = bias[col];
#pragma unroll
            for (int r2 = 0; r2 < 4; ++r2) {
                float g = gelu_f(acc[i][j][r2] + bia);
                u16 h = f2bf(g);
                size_t o = (size_t)(row0 + r2) * HID + col;
                Yh[o] = h;
                Yl[o] = f2bf(g - bf2f(h));
            }
        }
    }
}

// ---------------------------------------------------------------------------
// K6: output layer for BOTH steps + DDIM + tanh + FK + select + write d_out.
// One wave per batch element; lanes 0 and 1 run FK for step 0/1 in parallel.
// ---------------------------------------------------------------------------
__device__ void mat4mul(float C[4][4], const float A[4][4], const float Bm[4][4]) {
#pragma unroll
    for (int i = 0; i < 4; ++i)
#pragma unroll
        for (int j = 0; j < 4; ++j) {
            float s = A[i][0] * Bm[0][j];
            s += A[i][1] * Bm[1][j];
            s += A[i][2] * Bm[2][j];
            s += A[i][3] * Bm[3][j];
            C[i][j] = s;
        }
}

__global__ __launch_bounds__(256) void k_out_fk3(
        const u16* __restrict__ Yh, const u16* __restrict__ Yl,
        const float* __restrict__ W_out, const float* __restrict__ b_out,
        const float* __restrict__ noise, const float* __restrict__ x_pre,
        float* __restrict__ out, float c1, float c2, float c3) {
    int b = blockIdx.x * 4 + (threadIdx.x >> 6);
    int lane = threadIdx.x & 63;

    float acc0[8] = {0, 0, 0, 0, 0, 0, 0, 0};
    float acc1[8] = {0, 0, 0, 0, 0, 0, 0, 0};
    const u16* yh0 = &Yh[(size_t)b * HID];
    const u16* yl0 = &Yl[(size_t)b * HID];
    const u16* yh1 = &Yh[(size_t)(BATCH + b) * HID];
    const u16* yl1 = &Yl[(size_t)(BATCH + b) * HID];
#pragma unroll
    for (int it = 0; it < 8; ++it) {
        int k = lane + it * 64;
        float4 w0 = ((const float4*)&W_out[k * NACT])[0];
        float4 w1 = ((const float4*)&W_out[k * NACT])[1];
        float ya = bf2f(yh0[k]) + bf2f(yl0[k]);
        float yb = bf2f(yh1[k]) + bf2f(yl1[k]);
        acc0[0] += ya * w0.x; acc0[1] += ya * w0.y; acc0[2] += ya * w0.z; acc0[3] += ya * w0.w;
        acc0[4] += ya * w1.x; acc0[5] += ya * w1.y; acc0[6] += ya * w1.z; acc0[7] += ya * w1.w;
        acc1[0] += yb * w0.x; acc1[1] += yb * w0.y; acc1[2] += yb * w0.z; acc1[3] += yb * w0.w;
        acc1[4] += yb * w1.x; acc1[5] += yb * w1.y; acc1[6] += yb * w1.z; acc1[7] += yb * w1.w;
    }
    // butterfly reduce: all lanes end with full sums
#pragma unroll
    for (int n = 0; n < 8; ++n) {
#pragma unroll
        for (int off = 32; off > 0; off >>= 1) {
            acc0[n] += __shfl_xor(acc0[n], off, 64);
            acc1[n] += __shfl_xor(acc1[n], off, 64);
        }
    }

    float jq[8] = {0, 0, 0, 0, 0, 0, 0, 0};
    float err = 0.f;
    if (lane < 2) {
        int s = lane;
        const float* accp = (s == 0) ? acc0 : acc1;
        const float HIf[8] = {
            (float)(35.0 * M_PI / 180.0), (float)(-60.0 * M_PI / 180.0), 3.94f,
            (float)(155.0 * M_PI / 180.0), (float)(-55.0 * M_PI / 180.0),
            (float)M_PI, (float)(5.0 * M_PI / 180.0), 3.71f};
        const float LOf[8] = {
            (float)(-35.0 * M_PI / 180.0), (float)(-155.0 * M_PI / 180.0), 2.59f,
            (float)(60.0 * M_PI / 180.0), (float)(-125.0 * M_PI / 180.0),
            (float)(-M_PI), (float)(-90.0 * M_PI / 180.0), 2.5f};
        const float* nzp = &noise[(s * BATCH + b) * NACT];
#pragma unroll
        for (int n = 0; n < 8; ++n) {
            float o = accp[n] + b_out[n];
            float z = c1 * nzp[n] + c2 * o + c3 * nzp[n];
            float jn = (tanhf(z * 0.1f) + 1.0f) * 0.5f;
            jq[n] = jn * (HIf[n] - LOf[n]) + LOf[n];
        }
        const float a_[8]  = {0.0f, 0.16f, 0.07f, 0.0f, 0.1334f, 0.0f, 0.15f, 0.3625f};
        const float ca_[8] = {1.f, 0.f, 0.f, 0.f, 0.f, 0.f, 0.f, 0.f};
        const float sa_[8] = {0.f, -1.f, -1.f, 1.f, -1.f, -1.f, 1.f, -1.f};
        float d_[8] = {0.0f, 0.0f, jq[2], 0.0f, -0.1316f, 1.0105f, 0.52f, jq[7]};
        float th[8] = {jq[0], jq[1], 0.0f, jq[3], jq[4], jq[5], jq[6], 0.0f};
        float T[4][4], M[4][4], Tn[4][4];
#pragma unroll
        for (int j = 0; j < 8; ++j) {
            float ct = cosf(th[j]);
            float st = sinf(th[j]);
            M[0][0] = ct;          M[0][1] = -st;         M[0][2] = 0.0f;    M[0][3] = a_[j];
            M[1][0] = st * ca_[j]; M[1][1] = ct * ca_[j]; M[1][2] = -sa_[j]; M[1][3] = -sa_[j] * d_[j];
            M[2][0] = st * sa_[j]; M[2][1] = ct * sa_[j]; M[2][2] = ca_[j];  M[2][3] = ca_[j] * d_[j];
            M[3][0] = 0.0f;        M[3][1] = 0.0f;        M[3][2] = 0.0f;    M[3][3] = 1.0f;
            if (j == 0) {
#pragma unroll
                for (int i = 0; i < 4; ++i)
#pragma unroll
                    for (int cc = 0; cc < 4; ++cc) T[i][cc] = M[i][cc];
            } else {
                mat4mul(Tn, T, M);
#pragma unroll
                for (int i = 0; i < 4; ++i)
#pragma unroll
                    for (int cc = 0; cc < 4; ++cc) T[i][cc] = Tn[i][cc];
            }
        }
        float e1x = T[0][2] * 3.75f;
        float e1y = T[1][2] * 3.75f;
        float e1z = T[2][2] * 3.75f;
        float p0 = T[0][3];
        float p1 = T[1][3];
        float p2 = T[2][3] + 1.702f;
        float p3 = e1x + T[0][3];
        float p4 = e1y + T[1][3];
        float p5 = e1z + T[2][3] + 1.702f;
        const float* xp = &x_pre[b * 6];
        float dx0 = 100.0f * p0 - xp[0];
        float dx1 = 100.0f * p1 - xp[1];
        float dx2 = 100.0f * p2 - xp[2];
        float dx3 = 100.0f * p3 - xp[3];
        float dx4 = 100.0f * p4 - xp[4];
        float dx5 = 100.0f * p5 - xp[5];
        err = sqrtf(dx0 * dx0 + dx1 * dx1 + dx2 * dx2) +
              sqrtf(dx3 * dx3 + dx4 * dx4 + dx5 * dx5);
    }
    float e0 = __shfl(err, 0, 64);
    float e1 = __shfl(err, 1, 64);
    int sel = (e1 < e0) ? 1 : 0;   // first index wins ties
    float jsel[8];
#pragma unroll
    for (int n = 0; n < 8; ++n) jsel[n] = __shfl(jq[n], sel, 64);
    if (lane == 0) {
#pragma unroll
        for (int n = 0; n < 8; ++n) out[b * NACT + n] = jsel[n];
    }
}

// ===========================================================================
extern "C" void kernel_launch(void* const* d_in, const int* in_sizes, int n_in,
                              void* d_out, int out_size, void* d_ws, size_t ws_size,
                              hipStream_t stream) {
    const float* x_pre = (const float*)d_in[0];
    const float* noise = (const float*)d_in[1];
    const float* W_in  = (const float*)d_in[2];
    const float* b_in  = (const float*)d_in[3];
    const float* W1    = (const float*)d_in[4];
    const float* b1    = (const float*)d_in[5];
    const float* W2    = (const float*)d_in[6];
    const float* b2    = (const float*)d_in[7];
    const float* W3    = (const float*)d_in[8];
    const float* b3    = (const float*)d_in[9];
    const float* W4    = (const float*)d_in[10];
    const float* b4    = (const float*)d_in[11];
    const float* W_out = (const float*)d_in[12];
    const float* b_out = (const float*)d_in[13];

    // DDIM last-step coefficients (only the last loop iteration matters:
    // z is overwritten every iteration in the reference, nz never updated).
    double ab_c = exp(-0.1 * 50.0 / 1000.0 - 0.5 * (10.0 - 0.1) * 2500.0 / 1.0e6);
    float c1 = (float)sqrt(1.0 / ab_c);
    float c2 = (float)(-sqrt((1.0 - ab_c) / ab_c));
    float c3 = (float)sqrt(1.0 - ab_c);

    char* base = (char*)d_ws;
    u16* Ah = (u16*)base;                    // 4096x512 u16 = 4 MB
    u16* Al = Ah + 2097152;
    u16* Bh = Al + 2097152;
    u16* Bl = Bh + 2097152;
    u16* wt = (u16*)(base + 16777216);       // 4 layers x (hi,lo) [n][k] = 4 MB
    float* partials  = (float*)(base + 16777216 + 4194304); // 16x512
    float* bias_comb = partials + 16 * HID;

    k_prep<<<dim3(16, 16, 5), 256, 0, stream>>>(W1, W2, W3, W4, W_in, wt, partials);
    k_setup2<<<1, 512, 0, stream>>>(b_in, partials, bias_comb);
    k_layer_in2<<<ROWS * HID / 256, 256, 0, stream>>>(x_pre, noise, W_in, bias_comb, Ah, Al);
    dim3 g(ROWS / 64, HID / 64);
    k_gemm_mfma3<<<g, 256, 0, stream>>>(Ah, Al, wt + 0 * 524288, wt + 0 * 524288 + 262144, b1, Bh, Bl);
    k_gemm_mfma3<<<g, 256, 0, stream>>>(Bh, Bl, wt + 1 * 524288, wt + 1 * 524288 + 262144, b2, Ah, Al);
    k_gemm_mfma3<<<g, 256, 0, stream>>>(Ah, Al, wt + 2 * 524288, wt + 2 * 524288 + 262144, b3, Bh, Bl);
    k_gemm_mfma3<<<g, 256, 0, stream>>>(Bh, Bl, wt + 3 * 524288, wt + 3 * 524288 + 262144, b4, Ah, Al);
    k_out_fk3<<<BATCH / 4, 256, 0, stream>>>(Ah, Al, W_out, b_out, noise, x_pre,
                                             (float*)d_out, c1, c2, c3);
}

// Round 5
// 114.680 us; speedup vs baseline: 1.2687x; 1.0009x over previous
//
#include <hip/hip_runtime.h>
#include <math.h>

typedef __bf16 bf16x8 __attribute__((ext_vector_type(8)));
typedef float f32x4 __attribute__((ext_vector_type(4)));
typedef unsigned short u16;
typedef unsigned int u32;

constexpr int BATCH = 2048;
constexpr int ROWS  = 4096;   // 2 steps x 2048
constexpr int HID   = 512;
constexpr int NACT  = 8;

__device__ __forceinline__ float gelu_f(float x) {
    return 0.5f * x * (1.0f + erff(x * 0.70710678118654752f));
}
__device__ __forceinline__ u16 f2bf(float f) {
    u32 u = __float_as_uint(f);
    return (u16)((u + 0x7FFFu + ((u >> 16) & 1u)) >> 16);
}
__device__ __forceinline__ float bf2f(u16 h) {
    return __uint_as_float(((u32)h) << 16);
}

// ---------------------------------------------------------------------------
// K_prep: z<4 -> transpose + hi/lo-split weight layer z into wt
//         z==4 (x<4, y==0) -> bias_comb = b_in + temb @ W_in[14:526]
//           via 4-block split-K + last-block-wins reduction (mod-4 atomic
//           ticket: correct from ANY initial counter value, incl. 0xAA poison;
//           no spin -> no deadlock; deterministic work per call).
// wt layout per layer l: hi plane [n][k] at l*524288 (u16), lo at +262144
// ---------------------------------------------------------------------------
__global__ __launch_bounds__(256) void k_prep(
        const float* __restrict__ W1, const float* __restrict__ W2,
        const float* __restrict__ W3, const float* __restrict__ W4,
        const float* __restrict__ W_in, const float* __restrict__ b_in,
        u16* __restrict__ wt, float* __restrict__ partials,
        float* __restrict__ bias_comb, u32* __restrict__ ctr) {
    int z = blockIdx.z;
    if (z == 4) {
        if (blockIdx.x >= 4 || blockIdx.y != 0) return;
        __shared__ float temb[128];
        __shared__ u32 winner_s;
        int x = blockIdx.x, t = threadIdx.x;
        if (t < 128) {
            int k = x * 128 + t;
            int p = k >> 1;
            float div = expf((float)(2 * p) * (-9.210340371976184f / 512.0f));
            temb[t] = (k & 1) ? cosf(49.0f * div) : sinf(49.0f * div);
        }
        __syncthreads();
#pragma unroll
        for (int half = 0; half < 2; ++half) {
            int col = half * 256 + t;
            float acc = 0.f;
            for (int kk = 0; kk < 128; ++kk)
                acc += temb[kk] * W_in[(size_t)(14 + x * 128 + kk) * HID + col];
            partials[x * HID + col] = acc;
        }
        __threadfence();
        __syncthreads();
        if (t == 0) {
            u32 ret = atomicAdd(ctr, 1u);
            winner_s = ((ret & 3u) == 3u) ? 1u : 0u;
        }
        __syncthreads();
        if (winner_s) {
            __threadfence();
#pragma unroll
            for (int half = 0; half < 2; ++half) {
                int col = half * 256 + t;
                float a = b_in[col];
#pragma unroll
                for (int xx = 0; xx < 4; ++xx) a += partials[xx * HID + col];
                bias_comb[col] = a;
            }
        }
        return;
    }
    __shared__ float tile[32][33];
    const float* Ws[4] = {W1, W2, W3, W4};
    const float* W = Ws[z];
    u16* wh = wt + (size_t)z * 524288;
    u16* wl = wh + 262144;
    int kt = blockIdx.x * 32, nt = blockIdx.y * 32, t = threadIdx.x;
    int c = t & 31, r = t >> 5;
#pragma unroll
    for (int p = 0; p < 4; ++p)
        tile[r + p * 8][c] = W[(size_t)(kt + r + p * 8) * HID + nt + c];
    __syncthreads();
#pragma unroll
    for (int p = 0; p < 4; ++p) {
        int nl = r + p * 8, kl = c;
        float v = tile[kl][nl];
        u16 h = f2bf(v);
        u16 l2 = f2bf(v - bf2f(h));
        size_t o = (size_t)(nt + nl) * HID + kt + kl;
        wh[o] = h;
        wl[o] = l2;
    }
}

// ---------------------------------------------------------------------------
// K1: input layer -> bf16 hi/lo planes
// ---------------------------------------------------------------------------
__global__ __launch_bounds__(256) void k_layer_in2(
        const float* __restrict__ x_pre, const float* __restrict__ noise,
        const float* __restrict__ W_in, const float* __restrict__ bias_comb,
        u16* __restrict__ Yh, u16* __restrict__ Yl) {
    int idx = blockIdx.x * 256 + threadIdx.x;
    int r = idx >> 9, n = idx & 511, s = r >> 11, b = r & 2047;
    float acc = bias_comb[n];
    const float* xp = &x_pre[b * 6];
#pragma unroll
    for (int j = 0; j < 6; ++j) acc += xp[j] * W_in[j * HID + n];
    const float* nz = &noise[(s * BATCH + b) * NACT];
#pragma unroll
    for (int j = 0; j < 8; ++j) acc += nz[j] * W_in[(6 + j) * HID + n];
    float g = gelu_f(acc);
    u16 h = f2bf(g);
    Yh[idx] = h;
    Yl[idx] = f2bf(g - bf2f(h));
}

// ---------------------------------------------------------------------------
// GEMM: Y = gelu(A @ W + b) via split-bf16 3-pass MFMA.
// BM=BN=64, 8 waves (512 thr), wave tile 16x32 (2 frag cols), BK=32.
// Grid 512 blocks = 2/CU -> 16 waves/CU (4/SIMD) to hide staging latency.
// T3/T4: 3 LDS buffers, 2-deep prefetch, counted vmcnt(2) (never 0 in-loop),
// ONE raw s_barrier per K-step. Staging: wave w owns plane w>>1, two 16-row
// groups 2*(w&1), 2*(w&1)+1 (2 global_load_lds of 16B per wave per step).
// Safety: stage(c+2) overwrites buf[(c-1)%3]; its readers issued their MFMAs
// (which force lgkmcnt wait on the ds_reads) before arriving at the top-of-c
// barrier, which every wave passed before anyone issues stage(c+2).
// ---------------------------------------------------------------------------
__global__ __launch_bounds__(512) void k_gemm_mfma4(
        const u16* __restrict__ Ah, const u16* __restrict__ Al,
        const u16* __restrict__ Wh, const u16* __restrict__ Wl,
        const float* __restrict__ bias,
        u16* __restrict__ Yh, u16* __restrict__ Yl) {
    __shared__ __align__(16) u16 lds[3][4][4][512]; // [buf][plane Ah,Al,Wh,Wl][grp16][16x32]
    int tid = threadIdx.x, lane = tid & 63, w = tid >> 6;
    int wm = w >> 1;          // 0..3 : 16-row tile
    int wn = w & 1;           // 0..1 : 32-col tile
    int m0 = blockIdx.x * 64, n0 = blockIdx.y * 64;
    int l15 = lane & 15, k8 = (lane >> 4) * 8;

    // staging: wave w stages plane p = w>>1, groups g0 = 2*(w&1), g0+1
    int p  = w >> 1;
    int g0 = (w & 1) * 2;
    const u16* pl   = (p == 0) ? Ah : (p == 1) ? Al : (p == 2) ? Wh : Wl;
    int rowbase     = (p < 2) ? m0 : n0;
    const u16* src0 = pl + (size_t)(rowbase + g0 * 16 + l15) * HID + k8;
    const u16* src1 = src0 + 16 * HID;

    auto stage = [&](int c, int bb) {
        int off = c * 32;
        __builtin_amdgcn_global_load_lds((const __attribute__((address_space(1))) void*)(src0 + off),
            (__attribute__((address_space(3))) void*)&lds[bb][p][g0][0], 16, 0, 0);
        __builtin_amdgcn_global_load_lds((const __attribute__((address_space(1))) void*)(src1 + off),
            (__attribute__((address_space(3))) void*)&lds[bb][p][g0 + 1][0], 16, 0, 0);
    };

    f32x4 zero = {0.f, 0.f, 0.f, 0.f};
    f32x4 acc[2] = {zero, zero};

    stage(0, 0);
    stage(1, 1);
#pragma unroll
    for (int c = 0; c < 16; ++c) {
        int bb = c % 3;
        if (c < 15) {
            asm volatile("s_waitcnt vmcnt(2)" ::: "memory");
        } else {
            asm volatile("s_waitcnt vmcnt(0)" ::: "memory");
        }
        __builtin_amdgcn_s_barrier();
        __builtin_amdgcn_sched_barrier(0);

        bf16x8 ah, al, bh[2], bl[2];
        ah = *(const bf16x8*)&lds[bb][0][wm][lane * 8];
        al = *(const bf16x8*)&lds[bb][1][wm][lane * 8];
#pragma unroll
        for (int j = 0; j < 2; ++j) {
            bh[j] = *(const bf16x8*)&lds[bb][2][wn * 2 + j][lane * 8];
            bl[j] = *(const bf16x8*)&lds[bb][3][wn * 2 + j][lane * 8];
        }
        __builtin_amdgcn_s_setprio(1);
#pragma unroll
        for (int j = 0; j < 2; ++j) {
            acc[j] = __builtin_amdgcn_mfma_f32_16x16x32_bf16(ah, bh[j], acc[j], 0, 0, 0);
            acc[j] = __builtin_amdgcn_mfma_f32_16x16x32_bf16(ah, bl[j], acc[j], 0, 0, 0);
            acc[j] = __builtin_amdgcn_mfma_f32_16x16x32_bf16(al, bh[j], acc[j], 0, 0, 0);
        }
        __builtin_amdgcn_s_setprio(0);
        if (c < 14) stage(c + 2, (c + 2) % 3);
    }

    int row0 = m0 + wm * 16 + (lane >> 4) * 4;
#pragma unroll
    for (int j = 0; j < 2; ++j) {
        int col = n0 + wn * 32 + j * 16 + l15;
        float bia = bias[col];
#pragma unroll
        for (int r2 = 0; r2 < 4; ++r2) {
            float g = gelu_f(acc[j][r2] + bia);
            u16 h = f2bf(g);
            size_t o = (size_t)(row0 + r2) * HID + col;
            Yh[o] = h;
            Yl[o] = f2bf(g - bf2f(h));
        }
    }
}

// ---------------------------------------------------------------------------
// K6: output layer for BOTH steps + DDIM + tanh + FK + select + write d_out.
// One wave per batch element; lanes 0 and 1 run FK for step 0/1 in parallel.
// ---------------------------------------------------------------------------
__device__ void mat4mul(float C[4][4], const float A[4][4], const float Bm[4][4]) {
#pragma unroll
    for (int i = 0; i < 4; ++i)
#pragma unroll
        for (int j = 0; j < 4; ++j) {
            float s = A[i][0] * Bm[0][j];
            s += A[i][1] * Bm[1][j];
            s += A[i][2] * Bm[2][j];
            s += A[i][3] * Bm[3][j];
            C[i][j] = s;
        }
}

__global__ __launch_bounds__(256) void k_out_fk3(
        const u16* __restrict__ Yh, const u16* __restrict__ Yl,
        const float* __restrict__ W_out, const float* __restrict__ b_out,
        const float* __restrict__ noise, const float* __restrict__ x_pre,
        float* __restrict__ out, float c1, float c2, float c3) {
    int b = blockIdx.x * 4 + (threadIdx.x >> 6);
    int lane = threadIdx.x & 63;

    float acc0[8] = {0, 0, 0, 0, 0, 0, 0, 0};
    float acc1[8] = {0, 0, 0, 0, 0, 0, 0, 0};
    const u16* yh0 = &Yh[(size_t)b * HID];
    const u16* yl0 = &Yl[(size_t)b * HID];
    const u16* yh1 = &Yh[(size_t)(BATCH + b) * HID];
    const u16* yl1 = &Yl[(size_t)(BATCH + b) * HID];
#pragma unroll
    for (int it = 0; it < 8; ++it) {
        int k = lane + it * 64;
        float4 w0 = ((const float4*)&W_out[k * NACT])[0];
        float4 w1 = ((const float4*)&W_out[k * NACT])[1];
        float ya = bf2f(yh0[k]) + bf2f(yl0[k]);
        float yb = bf2f(yh1[k]) + bf2f(yl1[k]);
        acc0[0] += ya * w0.x; acc0[1] += ya * w0.y; acc0[2] += ya * w0.z; acc0[3] += ya * w0.w;
        acc0[4] += ya * w1.x; acc0[5] += ya * w1.y; acc0[6] += ya * w1.z; acc0[7] += ya * w1.w;
        acc1[0] += yb * w0.x; acc1[1] += yb * w0.y; acc1[2] += yb * w0.z; acc1[3] += yb * w0.w;
        acc1[4] += yb * w1.x; acc1[5] += yb * w1.y; acc1[6] += yb * w1.z; acc1[7] += yb * w1.w;
    }
    // butterfly reduce: all lanes end with full sums
#pragma unroll
    for (int n = 0; n < 8; ++n) {
#pragma unroll
        for (int off = 32; off > 0; off >>= 1) {
            acc0[n] += __shfl_xor(acc0[n], off, 64);
            acc1[n] += __shfl_xor(acc1[n], off, 64);
        }
    }

    float jq[8] = {0, 0, 0, 0, 0, 0, 0, 0};
    float err = 0.f;
    if (lane < 2) {
        int s = lane;
        const float* accp = (s == 0) ? acc0 : acc1;
        const float HIf[8] = {
            (float)(35.0 * M_PI / 180.0), (float)(-60.0 * M_PI / 180.0), 3.94f,
            (float)(155.0 * M_PI / 180.0), (float)(-55.0 * M_PI / 180.0),
            (float)M_PI, (float)(5.0 * M_PI / 180.0), 3.71f};
        const float LOf[8] = {
            (float)(-35.0 * M_PI / 180.0), (float)(-155.0 * M_PI / 180.0), 2.59f,
            (float)(60.0 * M_PI / 180.0), (float)(-125.0 * M_PI / 180.0),
            (float)(-M_PI), (float)(-90.0 * M_PI / 180.0), 2.5f};
        const float* nzp = &noise[(s * BATCH + b) * NACT];
#pragma unroll
        for (int n = 0; n < 8; ++n) {
            float o = accp[n] + b_out[n];
            float z = c1 * nzp[n] + c2 * o + c3 * nzp[n];
            float jn = (tanhf(z * 0.1f) + 1.0f) * 0.5f;
            jq[n] = jn * (HIf[n] - LOf[n]) + LOf[n];
        }
        const float a_[8]  = {0.0f, 0.16f, 0.07f, 0.0f, 0.1334f, 0.0f, 0.15f, 0.3625f};
        const float ca_[8] = {1.f, 0.f, 0.f, 0.f, 0.f, 0.f, 0.f, 0.f};
        const float sa_[8] = {0.f, -1.f, -1.f, 1.f, -1.f, -1.f, 1.f, -1.f};
        float d_[8] = {0.0f, 0.0f, jq[2], 0.0f, -0.1316f, 1.0105f, 0.52f, jq[7]};
        float th[8] = {jq[0], jq[1], 0.0f, jq[3], jq[4], jq[5], jq[6], 0.0f};
        float T[4][4], M[4][4], Tn[4][4];
#pragma unroll
        for (int j = 0; j < 8; ++j) {
            float ct = cosf(th[j]);
            float st = sinf(th[j]);
            M[0][0] = ct;          M[0][1] = -st;         M[0][2] = 0.0f;    M[0][3] = a_[j];
            M[1][0] = st * ca_[j]; M[1][1] = ct * ca_[j]; M[1][2] = -sa_[j]; M[1][3] = -sa_[j] * d_[j];
            M[2][0] = st * sa_[j]; M[2][1] = ct * sa_[j]; M[2][2] = ca_[j];  M[2][3] = ca_[j] * d_[j];
            M[3][0] = 0.0f;        M[3][1] = 0.0f;        M[3][2] = 0.0f;    M[3][3] = 1.0f;
            if (j == 0) {
#pragma unroll
                for (int i = 0; i < 4; ++i)
#pragma unroll
                    for (int cc = 0; cc < 4; ++cc) T[i][cc] = M[i][cc];
            } else {
                mat4mul(Tn, T, M);
#pragma unroll
                for (int i = 0; i < 4; ++i)
#pragma unroll
                    for (int cc = 0; cc < 4; ++cc) T[i][cc] = Tn[i][cc];
            }
        }
        float e1x = T[0][2] * 3.75f;
        float e1y = T[1][2] * 3.75f;
        float e1z = T[2][2] * 3.75f;
        float p0 = T[0][3];
        float p1 = T[1][3];
        float p2 = T[2][3] + 1.702f;
        float p3 = e1x + T[0][3];
        float p4 = e1y + T[1][3];
        float p5 = e1z + T[2][3] + 1.702f;
        const float* xp = &x_pre[b * 6];
        float dx0 = 100.0f * p0 - xp[0];
        float dx1 = 100.0f * p1 - xp[1];
        float dx2 = 100.0f * p2 - xp[2];
        float dx3 = 100.0f * p3 - xp[3];
        float dx4 = 100.0f * p4 - xp[4];
        float dx5 = 100.0f * p5 - xp[5];
        err = sqrtf(dx0 * dx0 + dx1 * dx1 + dx2 * dx2) +
              sqrtf(dx3 * dx3 + dx4 * dx4 + dx5 * dx5);
    }
    float e0 = __shfl(err, 0, 64);
    float e1 = __shfl(err, 1, 64);
    int sel = (e1 < e0) ? 1 : 0;   // first index wins ties
    float jsel[8];
#pragma unroll
    for (int n = 0; n < 8; ++n) jsel[n] = __shfl(jq[n], sel, 64);
    if (lane == 0) {
#pragma unroll
        for (int n = 0; n < 8; ++n) out[b * NACT + n] = jsel[n];
    }
}

// ===========================================================================
extern "C" void kernel_launch(void* const* d_in, const int* in_sizes, int n_in,
                              void* d_out, int out_size, void* d_ws, size_t ws_size,
                              hipStream_t stream) {
    const float* x_pre = (const float*)d_in[0];
    const float* noise = (const float*)d_in[1];
    const float* W_in  = (const float*)d_in[2];
    const float* b_in  = (const float*)d_in[3];
    const float* W1    = (const float*)d_in[4];
    const float* b1    = (const float*)d_in[5];
    const float* W2    = (const float*)d_in[6];
    const float* b2    = (const float*)d_in[7];
    const float* W3    = (const float*)d_in[8];
    const float* b3    = (const float*)d_in[9];
    const float* W4    = (const float*)d_in[10];
    const float* b4    = (const float*)d_in[11];
    const float* W_out = (const float*)d_in[12];
    const float* b_out = (const float*)d_in[13];

    // DDIM last-step coefficients (only the last loop iteration matters:
    // z is overwritten every iteration in the reference, nz never updated).
    double ab_c = exp(-0.1 * 50.0 / 1000.0 - 0.5 * (10.0 - 0.1) * 2500.0 / 1.0e6);
    float c1 = (float)sqrt(1.0 / ab_c);
    float c2 = (float)(-sqrt((1.0 - ab_c) / ab_c));
    float c3 = (float)sqrt(1.0 - ab_c);

    char* base = (char*)d_ws;
    u16* Ah = (u16*)base;                    // 4096x512 u16 = 4 MB
    u16* Al = Ah + 2097152;
    u16* Bh = Al + 2097152;
    u16* Bl = Bh + 2097152;
    u16* wt = (u16*)(base + 16777216);       // 4 layers x (hi,lo) [n][k] = 4 MB
    float* partials  = (float*)(base + 16777216 + 4194304); // 4x512
    float* bias_comb = partials + 4 * HID;
    u32*   ctr       = (u32*)(bias_comb + HID);

    k_prep<<<dim3(16, 16, 5), 256, 0, stream>>>(W1, W2, W3, W4, W_in, b_in,
                                                wt, partials, bias_comb, ctr);
    k_layer_in2<<<ROWS * HID / 256, 256, 0, stream>>>(x_pre, noise, W_in, bias_comb, Ah, Al);
    dim3 g(ROWS / 64, HID / 64);
    k_gemm_mfma4<<<g, 512, 0, stream>>>(Ah, Al, wt + 0 * 524288, wt + 0 * 524288 + 262144, b1, Bh, Bl);
    k_gemm_mfma4<<<g, 512, 0, stream>>>(Bh, Bl, wt + 1 * 524288, wt + 1 * 524288 + 262144, b2, Ah, Al);
    k_gemm_mfma4<<<g, 512, 0, stream>>>(Ah, Al, wt + 2 * 524288, wt + 2 * 524288 + 262144, b3, Bh, Bl);
    k_gemm_mfma4<<<g, 512, 0, stream>>>(Bh, Bl, wt + 3 * 524288, wt + 3 * 524288 + 262144, b4, Ah, Al);
    k_out_fk3<<<BATCH / 4, 256, 0, stream>>>(Ah, Al, W_out, b_out, noise, x_pre,
                                             (float*)d_out, c1, c2, c3);
}